// Round 1
// baseline (18448.311 us; speedup 1.0000x reference)
//
#include <hip/hip_runtime.h>
#include <cstdint>
#include <cstddef>

typedef _Float16 half8 __attribute__((ext_vector_type(8)));
typedef float    floatx4 __attribute__((ext_vector_type(4)));

#define B_  64
#define T_  512
#define D_  512
#define H_  512
#define NG  2048   // 4*H

// ---------------------------------------------------------------------------
// Kernel 1: input projections  XG[r][n] = x_row(r) . W_g[:,j] + b_g[j]
//   r = t*64 + b   (row-major [32768][2048], f16 storage in workspace)
//   n = g*512 + j
// f16 MFMA 16x16x32, 64x64 block tile, BK=32, 4 waves (each 16 rows x 64 cols)
// ---------------------------------------------------------------------------
__global__ __launch_bounds__(256) void proj_kernel(
    const float* __restrict__ x,
    const float* __restrict__ Wc, const float* __restrict__ Wi,
    const float* __restrict__ Wf, const float* __restrict__ Wo,
    const float* __restrict__ bc, const float* __restrict__ bi,
    const float* __restrict__ bf2, const float* __restrict__ bo,
    _Float16* __restrict__ XG)
{
  const int tiles_n = NG / 64;            // 32
  int tM = blockIdx.x / tiles_n;          // consecutive blocks share row tile -> L2 reuse of x
  int tN = blockIdx.x % tiles_n;
  int r0 = tM * 64;
  int t0 = r0 >> 6;                       // row tile == one timestep (64 batches)
  int n0 = tN * 64;
  int g  = n0 >> 9;                       // BN=64 divides 512 -> single gate per block
  const float* W    = (g==0) ? Wc : (g==1) ? Wi : (g==2) ? Wf : Wo;
  const float* bias = (g==0) ? bc : (g==1) ? bi : (g==2) ? bf2 : bo;
  int j0 = n0 & (H_-1);

  // padded stride 40 f16 (80 B): rows 16B-aligned, 2-way-max bank aliasing on b128
  __shared__ _Float16 Al[64*40];
  __shared__ _Float16 Bl[64*40];   // stored transposed: Bl[col][k]

  int tid  = threadIdx.x;
  int wave = tid >> 6;
  int lane = tid & 63;

  floatx4 acc[4] = {};

  int arow = tid >> 2;              // 0..63  (= batch b)
  int ak0  = (tid & 3) * 8;         // 0,8,16,24
  const float* xsrc = x + ((size_t)arow * T_ + t0) * D_;

  int bcol = tid & 63;
  int bk0  = (tid >> 6) * 8;

  for (int k0 = 0; k0 < D_; k0 += 32) {
    half8 av;
    #pragma unroll
    for (int i = 0; i < 8; ++i) av[i] = (_Float16)xsrc[k0 + ak0 + i];
    *(half8*)&Al[arow*40 + ak0] = av;

    half8 bv;
    #pragma unroll
    for (int i = 0; i < 8; ++i)
      bv[i] = (_Float16)W[(size_t)(k0 + bk0 + i) * H_ + j0 + bcol];
    *(half8*)&Bl[bcol*40 + bk0] = bv;

    __syncthreads();

    // A frag: lane holds A[row=lane&15][k=(lane>>4)*8 + i]
    half8 afrag = *(half8*)&Al[(wave*16 + (lane & 15))*40 + (lane >> 4)*8];
    #pragma unroll
    for (int ct = 0; ct < 4; ++ct) {
      // B frag: lane holds B[k=(lane>>4)*8+i][col=lane&15]  (Bl is [col][k])
      half8 bfrag = *(half8*)&Bl[(ct*16 + (lane & 15))*40 + (lane >> 4)*8];
      acc[ct] = __builtin_amdgcn_mfma_f32_16x16x32_f16(afrag, bfrag, acc[ct], 0, 0, 0);
    }
    __syncthreads();
  }

  // C/D layout (verified m89/m91): col = lane&15, row = (lane>>4)*4 + i
  #pragma unroll
  for (int ct = 0; ct < 4; ++ct) {
    int col = n0 + ct*16 + (lane & 15);
    float bvs = bias[col & (H_-1)];
    #pragma unroll
    for (int i = 0; i < 4; ++i) {
      int row = r0 + wave*16 + (lane >> 4)*4 + i;
      XG[(size_t)row * NG + col] = (_Float16)(acc[ct][i] + bvs);
    }
  }
}

// ---------------------------------------------------------------------------
// Kernel 2: persistent scan.
//   8 groups (blockIdx%8, XCD-aligned by round-robin) x 32 members.
//   Group owns batches [grp*8, grp*8+8); member owns 16 h-columns, all gates.
//   U slice (4 gates x 16 cols x 512, f32 = 128KB+pad) lives in LDS forever.
//   c state in registers. Per-step device-scope group barrier (monotone count).
// ---------------------------------------------------------------------------
#define SU 516   // f32 row stride: 16B aligned (516*4%16==0), bank step 4

__global__ __launch_bounds__(256) void scan_kernel(
    const _Float16* __restrict__ XG,
    const float* __restrict__ Uc, const float* __restrict__ Ui,
    const float* __restrict__ Uf, const float* __restrict__ Uo,
    float* __restrict__ out, float* __restrict__ h_buf,
    unsigned* __restrict__ cnt)
{
  extern __shared__ float lds[];
  float* U_lds   = lds;                  // 64 rows * SU   (row = g*16+jj, k-major)
  float* h_lds   = lds + 64*SU;          // 8 rows * SU
  float* pre_buf = lds + 64*SU + 8*SU;   // 8*16*2 gate-exchange

  int tid = threadIdx.x;
  int grp = blockIdx.x & 7;
  int member = blockIdx.x >> 3;
  int j0 = member * 16;

  { // one-time: stage U columns transposed into LDS
    int jj = tid & 15;
    int kk = tid >> 4;   // 0..15
    #pragma unroll
    for (int g = 0; g < 4; ++g) {
      const float* U = (g==0) ? Uc : (g==1) ? Ui : (g==2) ? Uf : Uo;
      float* dst = &U_lds[(g*16 + jj)*SU];
      for (int k = kk; k < H_; k += 16)
        dst[k] = U[(size_t)k * H_ + j0 + jj];
    }
  }
  for (int i = tid; i < 8*SU; i += 256) h_lds[i] = 0.0f;  // h_0 = 0
  __syncthreads();

  int b   = tid & 7;
  int jj  = (tid >> 3) & 15;
  int gh  = tid >> 7;             // wave-uniform: 0 -> gates (a=0,f=2); 1 -> (i=1,o=3)
  int bglob = grp*8 + b;
  int j = j0 + jj;

  const float* Ur0 = &U_lds[((gh    )*16 + jj)*SU];
  const float* Ur1 = &U_lds[((gh + 2)*16 + jj)*SU];
  const float* Hr  = &h_lds[b*SU];

  float c_reg = 0.0f;
  int p = 0;

  for (int t = 0; t < T_; ++t) {
    float acc0 = 0.f, acc1 = 0.f;
    #pragma unroll 4
    for (int k = 0; k < H_; k += 4) {
      float4 hv = *(const float4*)&Hr[k];
      float4 u0 = *(const float4*)&Ur0[k];
      float4 u1 = *(const float4*)&Ur1[k];
      acc0 = fmaf(hv.x, u0.x, acc0); acc0 = fmaf(hv.y, u0.y, acc0);
      acc0 = fmaf(hv.z, u0.z, acc0); acc0 = fmaf(hv.w, u0.w, acc0);
      acc1 = fmaf(hv.x, u1.x, acc1); acc1 = fmaf(hv.y, u1.y, acc1);
      acc1 = fmaf(hv.z, u1.z, acc1); acc1 = fmaf(hv.w, u1.w, acc1);
    }
    size_t xb = ((size_t)t * B_ + bglob) * NG;   // bias already folded into XG
    float pre0 = acc0 + (float)XG[xb + (size_t)gh*H_ + j];
    float pre1 = acc1 + (float)XG[xb + (size_t)(gh + 2)*H_ + j];

    __syncthreads();                   // all reads of h_lds / pre_buf done
    if (gh == 1) {
      pre_buf[(b*16 + jj)*2    ] = pre0;   // i
      pre_buf[(b*16 + jj)*2 + 1] = pre1;   // o
    }
    __syncthreads();
    if (gh == 0) {
      float pi = pre_buf[(b*16 + jj)*2];
      float po = pre_buf[(b*16 + jj)*2 + 1];
      float av = tanhf(pre0);
      float fv = 1.0f / (1.0f + __expf(-pre1));
      float iv = 1.0f / (1.0f + __expf(-pi));
      float ov = 1.0f / (1.0f + __expf(-po));
      float cn = fmaf(fv, c_reg, iv * av);
      c_reg = cn;
      float hval = ov * tanhf(cn);
      out[((size_t)bglob * T_ + t) * H_ + j] = hval;
      // agent-scope store: bypasses non-coherent XCD L2 for cross-WG visibility
      __hip_atomic_store(&h_buf[(size_t)(p^1)*(B_*H_) + bglob*H_ + j], hval,
                         __ATOMIC_RELAXED, __HIP_MEMORY_SCOPE_AGENT);
    }

    // ---- group barrier (monotone counter; re-zeroed by memset each launch) ----
    __threadfence();                   // release h_buf stores (agent scope)
    __syncthreads();
    if (tid == 0) {
      __hip_atomic_fetch_add(&cnt[grp*32], 1u, __ATOMIC_RELEASE, __HIP_MEMORY_SCOPE_AGENT);
      unsigned tgt = 32u * (unsigned)(t + 1);
      while (__hip_atomic_load(&cnt[grp*32], __ATOMIC_ACQUIRE, __HIP_MEMORY_SCOPE_AGENT) < tgt)
        __builtin_amdgcn_s_sleep(1);
    }
    __syncthreads();

    if (t + 1 < T_) {                  // stage h_{t} for next step
      p ^= 1;
      int row = tid >> 5;
      int c0  = (tid & 31) * 16;
      const float* src = &h_buf[(size_t)p*(B_*H_) + (size_t)(grp*8 + row)*H_ + c0];
      float* dst = &h_lds[row*SU + c0];
      #pragma unroll
      for (int q = 0; q < 16; ++q)
        dst[q] = __hip_atomic_load(&src[q], __ATOMIC_RELAXED, __HIP_MEMORY_SCOPE_AGENT);
      __syncthreads();
    }
  }
}

// ---------------------------------------------------------------------------
extern "C" void kernel_launch(void* const* d_in, const int* in_sizes, int n_in,
                              void* d_out, int out_size, void* d_ws, size_t ws_size,
                              hipStream_t stream)
{
  const float* x  = (const float*)d_in[0];
  const float* Wc = (const float*)d_in[1];
  const float* Wi = (const float*)d_in[2];
  const float* Wf = (const float*)d_in[3];
  const float* Wo = (const float*)d_in[4];
  const float* Uc = (const float*)d_in[5];
  const float* Ui = (const float*)d_in[6];
  const float* Uf = (const float*)d_in[7];
  const float* Uo = (const float*)d_in[8];
  const float* bc = (const float*)d_in[9];
  const float* bi = (const float*)d_in[10];
  const float* bf2= (const float*)d_in[11];
  const float* bo = (const float*)d_in[12];
  float* out = (float*)d_out;

  const size_t XG_BYTES = (size_t)T_ * B_ * NG * sizeof(_Float16);  // 128 MiB
  const size_t HB_BYTES = (size_t)2 * B_ * H_ * sizeof(float);      // 256 KiB
  const size_t CNT_BYTES = 8 * 32 * sizeof(unsigned);               // padded counters

  if (ws_size < XG_BYTES + HB_BYTES + CNT_BYTES) return;  // workspace too small

  _Float16* XG   = (_Float16*)d_ws;
  float*    hbuf = (float*)((char*)d_ws + XG_BYTES);
  unsigned* cnt  = (unsigned*)((char*)d_ws + XG_BYTES + HB_BYTES);

  hipMemsetAsync(cnt, 0, CNT_BYTES, stream);

  proj_kernel<<<dim3((T_*B_/64) * (NG/64)), dim3(256), 0, stream>>>(
      x, Wc, Wi, Wf, Wo, bc, bi, bf2, bo, XG);

  const int lds_bytes = (64*SU + 8*SU + 8*16*2) * (int)sizeof(float);  // 149,632 B
  hipFuncSetAttribute(reinterpret_cast<const void*>(scan_kernel),
                      hipFuncAttributeMaxDynamicSharedMemorySize, lds_bytes);
  scan_kernel<<<dim3(256), dim3(256), lds_bytes, stream>>>(
      XG, Uc, Ui, Uf, Uo, out, hbuf, cnt);
}

// Round 3
// 13722.021 us; speedup vs baseline: 1.3444x; 1.3444x over previous
//
#include <hip/hip_runtime.h>
#include <cstdint>
#include <cstddef>

typedef _Float16 half8  __attribute__((ext_vector_type(8)));
typedef _Float16 half2v __attribute__((ext_vector_type(2)));
typedef float    floatx4 __attribute__((ext_vector_type(4)));

#define B_  64
#define T_  512
#define D_  512
#define H_  512
#define NG  2048   // 4*H

#if defined(__has_builtin)
#if __has_builtin(__builtin_amdgcn_fdot2)
#define HAVE_FDOT2 1
#endif
#endif

static __device__ __forceinline__ float fdot2_acc(half2v a, half2v b, float c) {
#ifdef HAVE_FDOT2
  return __builtin_amdgcn_fdot2(a, b, c, false);
#else
  return fmaf((float)a[0], (float)b[0], fmaf((float)a[1], (float)b[1], c));
#endif
}
static __device__ __forceinline__ half2v h2(half8 v, int i) {
  half2v r; r[0] = v[2*i]; r[1] = v[2*i+1]; return r;
}

// ---------------------------------------------------------------------------
// Kernel 1: input projections (unchanged — measured ~0.17 ms)
// ---------------------------------------------------------------------------
__global__ __launch_bounds__(256) void proj_kernel(
    const float* __restrict__ x,
    const float* __restrict__ Wc, const float* __restrict__ Wi,
    const float* __restrict__ Wf, const float* __restrict__ Wo,
    const float* __restrict__ bc, const float* __restrict__ bi,
    const float* __restrict__ bf2, const float* __restrict__ bo,
    _Float16* __restrict__ XG)
{
  const int tiles_n = NG / 64;
  int tM = blockIdx.x / tiles_n;
  int tN = blockIdx.x % tiles_n;
  int r0 = tM * 64;
  int t0 = r0 >> 6;
  int n0 = tN * 64;
  int g  = n0 >> 9;
  const float* W    = (g==0) ? Wc : (g==1) ? Wi : (g==2) ? Wf : Wo;
  const float* bias = (g==0) ? bc : (g==1) ? bi : (g==2) ? bf2 : bo;
  int j0 = n0 & (H_-1);

  __shared__ _Float16 Al[64*40];
  __shared__ _Float16 Bl[64*40];

  int tid  = threadIdx.x;
  int wave = tid >> 6;
  int lane = tid & 63;

  floatx4 acc[4] = {};

  int arow = tid >> 2;
  int ak0  = (tid & 3) * 8;
  const float* xsrc = x + ((size_t)arow * T_ + t0) * D_;

  int bcol = tid & 63;
  int bk0  = (tid >> 6) * 8;

  for (int k0 = 0; k0 < D_; k0 += 32) {
    half8 av;
    #pragma unroll
    for (int i = 0; i < 8; ++i) av[i] = (_Float16)xsrc[k0 + ak0 + i];
    *(half8*)&Al[arow*40 + ak0] = av;

    half8 bv;
    #pragma unroll
    for (int i = 0; i < 8; ++i)
      bv[i] = (_Float16)W[(size_t)(k0 + bk0 + i) * H_ + j0 + bcol];
    *(half8*)&Bl[bcol*40 + bk0] = bv;

    __syncthreads();

    half8 afrag = *(half8*)&Al[(wave*16 + (lane & 15))*40 + (lane >> 4)*8];
    #pragma unroll
    for (int ct = 0; ct < 4; ++ct) {
      half8 bfrag = *(half8*)&Bl[(ct*16 + (lane & 15))*40 + (lane >> 4)*8];
      acc[ct] = __builtin_amdgcn_mfma_f32_16x16x32_f16(afrag, bfrag, acc[ct], 0, 0, 0);
    }
    __syncthreads();
  }

  #pragma unroll
  for (int ct = 0; ct < 4; ++ct) {
    int col = n0 + ct*16 + (lane & 15);
    float bvs = bias[col & (H_-1)];
    #pragma unroll
    for (int i = 0; i < 4; ++i) {
      int row = r0 + wave*16 + (lane >> 4)*4 + i;
      XG[(size_t)row * NG + col] = (_Float16)(acc[ct][i] + bvs);
    }
  }
}

// ---------------------------------------------------------------------------
// Kernel 2: persistent scan, v2.
//   - U in LDS as f16 (64 rows x SH), dots via v_dot2_f32_f16 (f32 accum)
//   - distributed flag-array barrier (no contended fetch_add)
//   - conflict-free linear b128 h staging
// ---------------------------------------------------------------------------
#define SH 520   // f16 row stride: 1040 B -> +4 banks per row; b128 reads conflict-free

__global__ __launch_bounds__(256) void scan_kernel(
    const _Float16* __restrict__ XG,
    const float* __restrict__ Uc, const float* __restrict__ Ui,
    const float* __restrict__ Uf, const float* __restrict__ Uo,
    float* __restrict__ out, float* __restrict__ h_buf,
    unsigned* __restrict__ flags)
{
  extern __shared__ _Float16 lds[];
  _Float16* U_lds = lds;                       // 64 rows x SH   (row = g*16+jj)
  _Float16* h_lds = lds + 64*SH;               // 8 rows x SH
  float*  pre_buf = (float*)(lds + 72*SH);     // 8*16*2 f32 gate exchange

  int tid = threadIdx.x;
  int grp = blockIdx.x & 7;
  int member = blockIdx.x >> 3;
  int j0 = member * 16;

  { // one-time: stage U columns transposed into LDS, f32 -> f16
    int jj = tid & 15;
    int kk = tid >> 4;
    #pragma unroll
    for (int g = 0; g < 4; ++g) {
      const float* U = (g==0) ? Uc : (g==1) ? Ui : (g==2) ? Uf : Uo;
      _Float16* dst = &U_lds[(g*16 + jj)*SH];
      for (int k = kk; k < H_; k += 16)
        dst[k] = (_Float16)U[(size_t)k * H_ + j0 + jj];
    }
  }
  for (int i = tid; i < 8*SH; i += 256) h_lds[i] = (_Float16)0.0f;  // h_0 = 0
  __syncthreads();

  int b   = tid & 7;
  int jj  = (tid >> 3) & 15;
  int gh  = tid >> 7;             // wave-uniform: 0 -> (a,f); 1 -> (i,o)
  int bglob = grp*8 + b;
  int j = j0 + jj;

  const half8* Ur0 = (const half8*)&U_lds[((gh    )*16 + jj)*SH];
  const half8* Ur1 = (const half8*)&U_lds[((gh + 2)*16 + jj)*SH];
  const half8* Hr  = (const half8*)&h_lds[b*SH];

  unsigned* grp_flags = &flags[grp*32];
  float c_reg = 0.0f;
  int p = 0;

  for (int t = 0; t < T_; ++t) {
    // XG loads issued early (bias already folded in)
    size_t xb = ((size_t)t * B_ + bglob) * NG;
    float xg0 = (float)XG[xb + (size_t)gh*H_ + j];
    float xg1 = (float)XG[xb + (size_t)(gh + 2)*H_ + j];

    float acc0 = 0.f, acc1 = 0.f;
    #pragma unroll 4
    for (int k8 = 0; k8 < H_/8; ++k8) {
      half8 hv = Hr[k8];
      half8 u0 = Ur0[k8];
      half8 u1 = Ur1[k8];
      #pragma unroll
      for (int i = 0; i < 4; ++i) {
        acc0 = fdot2_acc(h2(hv,i), h2(u0,i), acc0);
        acc1 = fdot2_acc(h2(hv,i), h2(u1,i), acc1);
      }
    }
    float pre0 = acc0 + xg0;
    float pre1 = acc1 + xg1;

    if (gh == 1) {
      pre_buf[(b*16 + jj)*2    ] = pre0;   // i
      pre_buf[(b*16 + jj)*2 + 1] = pre1;   // o
    }
    __syncthreads();
    if (gh == 0) {
      float pi = pre_buf[(b*16 + jj)*2];
      float po = pre_buf[(b*16 + jj)*2 + 1];
      float av = tanhf(pre0);
      float fv = 1.0f / (1.0f + __expf(-pre1));
      float iv = 1.0f / (1.0f + __expf(-pi));
      float ov = 1.0f / (1.0f + __expf(-po));
      float cn = fmaf(fv, c_reg, iv * av);
      c_reg = cn;
      float hval = ov * tanhf(cn);
      out[((size_t)bglob * T_ + t) * H_ + j] = hval;
      __hip_atomic_store(&h_buf[(size_t)(p^1)*(B_*H_) + (size_t)bglob*H_ + j], hval,
                         __ATOMIC_RELAXED, __HIP_MEMORY_SCOPE_AGENT);
    }

    // ---- distributed flag barrier (one release store/member, parallel poll) ----
    __builtin_amdgcn_fence(__ATOMIC_RELEASE, "agent");
    __syncthreads();   // all lanes' h stores ordered before the flag publish
    if (tid == 0)
      __hip_atomic_store(&grp_flags[member], (unsigned)(t + 1),
                         __ATOMIC_RELAXED, __HIP_MEMORY_SCOPE_AGENT);

    if (t + 1 < T_) {
      if (tid < 32) {
        while (__hip_atomic_load(&grp_flags[tid], __ATOMIC_RELAXED,
                                 __HIP_MEMORY_SCOPE_AGENT) < (unsigned)(t + 1))
          __builtin_amdgcn_s_sleep(1);
      }
      __syncthreads();
      __builtin_amdgcn_fence(__ATOMIC_ACQUIRE, "agent");

      // stage h_t: linear chunks -> conflict-free ds_write_b128
      p ^= 1;
      #pragma unroll
      for (int q = 0; q < 2; ++q) {
        int idx = tid + q*256;          // 0..511 chunks of 8 halfs
        int row = idx >> 6;             // batch row 0..7
        int ch  = idx & 63;             // chunk within row
        const float* src = &h_buf[(size_t)p*(B_*H_) + (size_t)(grp*8 + row)*H_ + ch*8];
        half8 hv;
        #pragma unroll
        for (int q2 = 0; q2 < 8; ++q2)
          hv[q2] = (_Float16)__hip_atomic_load(&src[q2], __ATOMIC_RELAXED,
                                               __HIP_MEMORY_SCOPE_AGENT);
        *(half8*)&h_lds[row*SH + ch*8] = hv;
      }
      __syncthreads();
    }
  }
}

// ---------------------------------------------------------------------------
extern "C" void kernel_launch(void* const* d_in, const int* in_sizes, int n_in,
                              void* d_out, int out_size, void* d_ws, size_t ws_size,
                              hipStream_t stream)
{
  const float* x  = (const float*)d_in[0];
  const float* Wc = (const float*)d_in[1];
  const float* Wi = (const float*)d_in[2];
  const float* Wf = (const float*)d_in[3];
  const float* Wo = (const float*)d_in[4];
  const float* Uc = (const float*)d_in[5];
  const float* Ui = (const float*)d_in[6];
  const float* Uf = (const float*)d_in[7];
  const float* Uo = (const float*)d_in[8];
  const float* bc = (const float*)d_in[9];
  const float* bi = (const float*)d_in[10];
  const float* bf2= (const float*)d_in[11];
  const float* bo = (const float*)d_in[12];
  float* out = (float*)d_out;

  const size_t XG_BYTES  = (size_t)T_ * B_ * NG * sizeof(_Float16);  // 128 MiB
  const size_t HB_BYTES  = (size_t)2 * B_ * H_ * sizeof(float);      // 256 KiB
  const size_t FLG_BYTES = 8 * 32 * sizeof(unsigned);

  if (ws_size < XG_BYTES + HB_BYTES + FLG_BYTES) return;

  _Float16* XG    = (_Float16*)d_ws;
  float*    hbuf  = (float*)((char*)d_ws + XG_BYTES);
  unsigned* flags = (unsigned*)((char*)d_ws + XG_BYTES + HB_BYTES);

  (void)hipMemsetAsync(flags, 0, FLG_BYTES, stream);

  proj_kernel<<<dim3((T_*B_/64) * (NG/64)), dim3(256), 0, stream>>>(
      x, Wc, Wi, Wf, Wo, bc, bi, bf2, bo, XG);

  const int lds_bytes = 72*SH*2 + 8*16*2*4;   // 75,904 B
  (void)hipFuncSetAttribute(reinterpret_cast<const void*>(scan_kernel),
                      hipFuncAttributeMaxDynamicSharedMemorySize, lds_bytes);
  scan_kernel<<<dim3(256), dim3(256), lds_bytes, stream>>>(
      XG, Uc, Ui, Uf, Uo, out, hbuf, flags);
}

// Round 4
// 7074.978 us; speedup vs baseline: 2.6075x; 1.9395x over previous
//
#include <hip/hip_runtime.h>
#include <cstdint>
#include <cstddef>

typedef _Float16 half8  __attribute__((ext_vector_type(8)));
typedef _Float16 half2v __attribute__((ext_vector_type(2)));
typedef float    floatx4 __attribute__((ext_vector_type(4)));

#define B_  64
#define T_  512
#define D_  512
#define H_  512
#define NG  2048   // 4*H

#if defined(__has_builtin)
#if __has_builtin(__builtin_amdgcn_fdot2)
#define HAVE_FDOT2 1
#endif
#endif

static __device__ __forceinline__ float fdot2_acc(half2v a, half2v b, float c) {
#ifdef HAVE_FDOT2
  return __builtin_amdgcn_fdot2(a, b, c, false);
#else
  return fmaf((float)a[0], (float)b[0], fmaf((float)a[1], (float)b[1], c));
#endif
}
static __device__ __forceinline__ half2v h2(half8 v, int i) {
  half2v r; r[0] = v[2*i]; r[1] = v[2*i+1]; return r;
}

// ---------------------------------------------------------------------------
// Kernel 1: input projections (unchanged — measured ~0.17 ms)
// ---------------------------------------------------------------------------
__global__ __launch_bounds__(256) void proj_kernel(
    const float* __restrict__ x,
    const float* __restrict__ Wc, const float* __restrict__ Wi,
    const float* __restrict__ Wf, const float* __restrict__ Wo,
    const float* __restrict__ bc, const float* __restrict__ bi,
    const float* __restrict__ bf2, const float* __restrict__ bo,
    _Float16* __restrict__ XG)
{
  const int tiles_n = NG / 64;
  int tM = blockIdx.x / tiles_n;
  int tN = blockIdx.x % tiles_n;
  int r0 = tM * 64;
  int t0 = r0 >> 6;
  int n0 = tN * 64;
  int g  = n0 >> 9;
  const float* W    = (g==0) ? Wc : (g==1) ? Wi : (g==2) ? Wf : Wo;
  const float* bias = (g==0) ? bc : (g==1) ? bi : (g==2) ? bf2 : bo;
  int j0 = n0 & (H_-1);

  __shared__ _Float16 Al[64*40];
  __shared__ _Float16 Bl[64*40];

  int tid  = threadIdx.x;
  int wave = tid >> 6;
  int lane = tid & 63;

  floatx4 acc[4] = {};

  int arow = tid >> 2;
  int ak0  = (tid & 3) * 8;
  const float* xsrc = x + ((size_t)arow * T_ + t0) * D_;

  int bcol = tid & 63;
  int bk0  = (tid >> 6) * 8;

  for (int k0 = 0; k0 < D_; k0 += 32) {
    half8 av;
    #pragma unroll
    for (int i = 0; i < 8; ++i) av[i] = (_Float16)xsrc[k0 + ak0 + i];
    *(half8*)&Al[arow*40 + ak0] = av;

    half8 bv;
    #pragma unroll
    for (int i = 0; i < 8; ++i)
      bv[i] = (_Float16)W[(size_t)(k0 + bk0 + i) * H_ + j0 + bcol];
    *(half8*)&Bl[bcol*40 + bk0] = bv;

    __syncthreads();

    half8 afrag = *(half8*)&Al[(wave*16 + (lane & 15))*40 + (lane >> 4)*8];
    #pragma unroll
    for (int ct = 0; ct < 4; ++ct) {
      half8 bfrag = *(half8*)&Bl[(ct*16 + (lane & 15))*40 + (lane >> 4)*8];
      acc[ct] = __builtin_amdgcn_mfma_f32_16x16x32_f16(afrag, bfrag, acc[ct], 0, 0, 0);
    }
    __syncthreads();
  }

  #pragma unroll
  for (int ct = 0; ct < 4; ++ct) {
    int col = n0 + ct*16 + (lane & 15);
    float bvs = bias[col & (H_-1)];
    #pragma unroll
    for (int i = 0; i < 4; ++i) {
      int row = r0 + wave*16 + (lane >> 4)*4 + i;
      XG[(size_t)row * NG + col] = (_Float16)(acc[ct][i] + bvs);
    }
  }
}

// ---------------------------------------------------------------------------
// Kernel 2: persistent scan, v3 — tagged-word handoff, NO fences, NO flags.
//   h exchange word: (f16 bits << 16) | (step tag & 0xFFFF), 32-bit relaxed
//   agent atomics. Double-buffered by t&1; slot reuse proven race-free by
//   the transitive publish dependency. memset each launch -> tag 0 = h_0 = 0.
// ---------------------------------------------------------------------------
#define SH 520   // f16 row stride

__global__ __launch_bounds__(256) void scan_kernel(
    const _Float16* __restrict__ XG,
    const float* __restrict__ Uc, const float* __restrict__ Ui,
    const float* __restrict__ Uf, const float* __restrict__ Uo,
    float* __restrict__ out, unsigned* __restrict__ h_buf)
{
  extern __shared__ _Float16 lds[];
  _Float16* U_lds = lds;                       // 64 rows x SH   (row = g*16+jj)
  _Float16* h_lds = lds + 64*SH;               // 8 rows x SH
  float*  pre_buf = (float*)(lds + 72*SH);     // 8*16*2 f32 gate exchange

  int tid = threadIdx.x;
  int grp = blockIdx.x & 7;
  int member = blockIdx.x >> 3;
  int j0 = member * 16;

  { // one-time: stage U columns transposed into LDS, f32 -> f16
    int jj = tid & 15;
    int kk = tid >> 4;
    #pragma unroll
    for (int g = 0; g < 4; ++g) {
      const float* U = (g==0) ? Uc : (g==1) ? Ui : (g==2) ? Uf : Uo;
      _Float16* dst = &U_lds[(g*16 + jj)*SH];
      for (int k = kk; k < H_; k += 16)
        dst[k] = (_Float16)U[(size_t)k * H_ + j0 + jj];
    }
  }
  __syncthreads();

  int b   = tid & 7;
  int jj  = (tid >> 3) & 15;
  int gh  = tid >> 7;             // wave-uniform: 0 -> (a,f); 1 -> (i,o)
  int bglob = grp*8 + b;
  int j = j0 + jj;

  const half8* Ur0 = (const half8*)&U_lds[((gh    )*16 + jj)*SH];
  const half8* Ur1 = (const half8*)&U_lds[((gh + 2)*16 + jj)*SH];
  const half8* Hr  = (const half8*)&h_lds[b*SH];

  // staging geometry: thread covers 16 consecutive cols of one batch row
  int srow = tid >> 5;            // 0..7
  int sc0  = (tid & 31) * 16;

  float c_reg = 0.0f;

  for (int t = 0; t < T_; ++t) {
    // ---- stage h^t (tagged words) into h_lds; the tag poll IS the sync ----
    {
      const unsigned* src = &h_buf[(size_t)(t & 1)*(B_*H_)
                                   + (size_t)(grp*8 + srow)*H_ + sc0];
      unsigned want = (unsigned)t & 0xFFFFu;
      unsigned w[16];
      #pragma unroll
      for (int q = 0; q < 16; ++q)
        w[q] = __hip_atomic_load(&src[q], __ATOMIC_RELAXED, __HIP_MEMORY_SCOPE_AGENT);
      #pragma unroll
      for (int q = 0; q < 16; ++q)
        while ((w[q] & 0xFFFFu) != want)
          w[q] = __hip_atomic_load(&src[q], __ATOMIC_RELAXED, __HIP_MEMORY_SCOPE_AGENT);
      half8 hv0, hv1;
      #pragma unroll
      for (int q = 0; q < 8; ++q) {
        hv0[q] = __builtin_bit_cast(_Float16, (unsigned short)(w[q] >> 16));
        hv1[q] = __builtin_bit_cast(_Float16, (unsigned short)(w[8+q] >> 16));
      }
      *(half8*)&h_lds[srow*SH + sc0]     = hv0;
      *(half8*)&h_lds[srow*SH + sc0 + 8] = hv1;
    }
    __syncthreads();   // staged h visible

    size_t xb = ((size_t)t * B_ + bglob) * NG;
    float xg0 = (float)XG[xb + (size_t)gh*H_ + j];
    float xg1 = (float)XG[xb + (size_t)(gh + 2)*H_ + j];

    float acc0 = 0.f, acc1 = 0.f;
    #pragma unroll 4
    for (int k8 = 0; k8 < H_/8; ++k8) {
      half8 hv = Hr[k8];
      half8 u0 = Ur0[k8];
      half8 u1 = Ur1[k8];
      #pragma unroll
      for (int i = 0; i < 4; ++i) {
        acc0 = fdot2_acc(h2(hv,i), h2(u0,i), acc0);
        acc1 = fdot2_acc(h2(hv,i), h2(u1,i), acc1);
      }
    }
    float pre0 = acc0 + xg0;
    float pre1 = acc1 + xg1;

    if (gh == 1) {
      pre_buf[(b*16 + jj)*2    ] = pre0;   // i
      pre_buf[(b*16 + jj)*2 + 1] = pre1;   // o
    }
    __syncthreads();   // pre_buf visible; all h_lds reads done (next stage may overwrite)

    if (gh == 0) {
      float pi = pre_buf[(b*16 + jj)*2];
      float po = pre_buf[(b*16 + jj)*2 + 1];
      float av = tanhf(pre0);
      float fv = 1.0f / (1.0f + __expf(-pre1));
      float iv = 1.0f / (1.0f + __expf(-pi));
      float ov = 1.0f / (1.0f + __expf(-po));
      float cn = fmaf(fv, c_reg, iv * av);
      c_reg = cn;
      float hval = ov * tanhf(cn);
      out[((size_t)bglob * T_ + t) * H_ + j] = hval;
      if (t + 1 < T_) {
        unsigned wv = ((unsigned)__builtin_bit_cast(unsigned short, (_Float16)hval) << 16)
                    | ((unsigned)(t + 1) & 0xFFFFu);
        __hip_atomic_store(&h_buf[(size_t)((t + 1) & 1)*(B_*H_) + (size_t)bglob*H_ + j],
                           wv, __ATOMIC_RELAXED, __HIP_MEMORY_SCOPE_AGENT);
      }
    }
  }
}

// ---------------------------------------------------------------------------
extern "C" void kernel_launch(void* const* d_in, const int* in_sizes, int n_in,
                              void* d_out, int out_size, void* d_ws, size_t ws_size,
                              hipStream_t stream)
{
  const float* x  = (const float*)d_in[0];
  const float* Wc = (const float*)d_in[1];
  const float* Wi = (const float*)d_in[2];
  const float* Wf = (const float*)d_in[3];
  const float* Wo = (const float*)d_in[4];
  const float* Uc = (const float*)d_in[5];
  const float* Ui = (const float*)d_in[6];
  const float* Uf = (const float*)d_in[7];
  const float* Uo = (const float*)d_in[8];
  const float* bc = (const float*)d_in[9];
  const float* bi = (const float*)d_in[10];
  const float* bf2= (const float*)d_in[11];
  const float* bo = (const float*)d_in[12];
  float* out = (float*)d_out;

  const size_t XG_BYTES = (size_t)T_ * B_ * NG * sizeof(_Float16);  // 128 MiB
  const size_t HB_BYTES = (size_t)2 * B_ * H_ * sizeof(unsigned);   // 256 KiB

  if (ws_size < XG_BYTES + HB_BYTES) return;

  _Float16* XG   = (_Float16*)d_ws;
  unsigned* hbuf = (unsigned*)((char*)d_ws + XG_BYTES);

  // tag 0 / h=0 initial state; also kills cross-replay tag aliasing
  (void)hipMemsetAsync(hbuf, 0, HB_BYTES, stream);

  proj_kernel<<<dim3((T_*B_/64) * (NG/64)), dim3(256), 0, stream>>>(
      x, Wc, Wi, Wf, Wo, bc, bi, bf2, bo, XG);

  const int lds_bytes = 72*SH*2 + 8*16*2*4;   // 75,904 B
  (void)hipFuncSetAttribute(reinterpret_cast<const void*>(scan_kernel),
                      hipFuncAttributeMaxDynamicSharedMemorySize, lds_bytes);
  scan_kernel<<<dim3(256), dim3(256), lds_bytes, stream>>>(
      XG, Uc, Ui, Uf, Uo, out, hbuf);
}

// Round 5
// 5358.162 us; speedup vs baseline: 3.4430x; 1.3204x over previous
//
#include <hip/hip_runtime.h>
#include <cstdint>
#include <cstddef>

typedef _Float16 half8  __attribute__((ext_vector_type(8)));
typedef _Float16 half2v __attribute__((ext_vector_type(2)));
typedef float    floatx4 __attribute__((ext_vector_type(4)));

#define B_  64
#define T_  512
#define D_  512
#define H_  512
#define NG  2048   // 4*H

#if defined(__has_builtin)
#if __has_builtin(__builtin_amdgcn_fdot2)
#define HAVE_FDOT2 1
#endif
#endif

static __device__ __forceinline__ float fdot2_acc(half2v a, half2v b, float c) {
#ifdef HAVE_FDOT2
  return __builtin_amdgcn_fdot2(a, b, c, false);
#else
  return fmaf((float)a[0], (float)b[0], fmaf((float)a[1], (float)b[1], c));
#endif
}
static __device__ __forceinline__ half2v h2(half8 v, int i) {
  half2v r; r[0] = v[2*i]; r[1] = v[2*i+1]; return r;
}
static __device__ __forceinline__ float fast_sigmoid(float x) {
  return 1.0f / (1.0f + __expf(-x));      // exp overflow -> 0, no NaN
}
static __device__ __forceinline__ float fast_tanh(float x) {
  x = fminf(15.0f, fmaxf(-15.0f, x));     // clamp so e never overflows
  float e = __expf(2.0f * x);
  return (e - 1.0f) / (e + 1.0f);
}

// ---------------------------------------------------------------------------
// Kernel 1: input projections (unchanged — measured ~0.17 ms)
// ---------------------------------------------------------------------------
__global__ __launch_bounds__(256) void proj_kernel(
    const float* __restrict__ x,
    const float* __restrict__ Wc, const float* __restrict__ Wi,
    const float* __restrict__ Wf, const float* __restrict__ Wo,
    const float* __restrict__ bc, const float* __restrict__ bi,
    const float* __restrict__ bf2, const float* __restrict__ bo,
    _Float16* __restrict__ XG)
{
  const int tiles_n = NG / 64;
  int tM = blockIdx.x / tiles_n;
  int tN = blockIdx.x % tiles_n;
  int r0 = tM * 64;
  int t0 = r0 >> 6;
  int n0 = tN * 64;
  int g  = n0 >> 9;
  const float* W    = (g==0) ? Wc : (g==1) ? Wi : (g==2) ? Wf : Wo;
  const float* bias = (g==0) ? bc : (g==1) ? bi : (g==2) ? bf2 : bo;
  int j0 = n0 & (H_-1);

  __shared__ _Float16 Al[64*40];
  __shared__ _Float16 Bl[64*40];

  int tid  = threadIdx.x;
  int wave = tid >> 6;
  int lane = tid & 63;

  floatx4 acc[4] = {};

  int arow = tid >> 2;
  int ak0  = (tid & 3) * 8;
  const float* xsrc = x + ((size_t)arow * T_ + t0) * D_;

  int bcol = tid & 63;
  int bk0  = (tid >> 6) * 8;

  for (int k0 = 0; k0 < D_; k0 += 32) {
    half8 av;
    #pragma unroll
    for (int i = 0; i < 8; ++i) av[i] = (_Float16)xsrc[k0 + ak0 + i];
    *(half8*)&Al[arow*40 + ak0] = av;

    half8 bv;
    #pragma unroll
    for (int i = 0; i < 8; ++i)
      bv[i] = (_Float16)W[(size_t)(k0 + bk0 + i) * H_ + j0 + bcol];
    *(half8*)&Bl[bcol*40 + bk0] = bv;

    __syncthreads();

    half8 afrag = *(half8*)&Al[(wave*16 + (lane & 15))*40 + (lane >> 4)*8];
    #pragma unroll
    for (int ct = 0; ct < 4; ++ct) {
      half8 bfrag = *(half8*)&Bl[(ct*16 + (lane & 15))*40 + (lane >> 4)*8];
      acc[ct] = __builtin_amdgcn_mfma_f32_16x16x32_f16(afrag, bfrag, acc[ct], 0, 0, 0);
    }
    __syncthreads();
  }

  #pragma unroll
  for (int ct = 0; ct < 4; ++ct) {
    int col = n0 + ct*16 + (lane & 15);
    float bvs = bias[col & (H_-1)];
    #pragma unroll
    for (int i = 0; i < 4; ++i) {
      int row = r0 + wave*16 + (lane >> 4)*4 + i;
      XG[(size_t)row * NG + col] = (_Float16)(acc[ct][i] + bvs);
    }
  }
}

// ---------------------------------------------------------------------------
// Kernel 2: persistent scan, v4 — tagged-word handoff + SWEEP-PARALLEL poll.
//   Each sweep: 8 independent 64-bit relaxed agent loads (2 words each),
//   one combined tag check -> one round-trip latency per sweep, not per word.
// ---------------------------------------------------------------------------
#define SH 520   // f16 row stride

__global__ __launch_bounds__(256) void scan_kernel(
    const _Float16* __restrict__ XG,
    const float* __restrict__ Uc, const float* __restrict__ Ui,
    const float* __restrict__ Uf, const float* __restrict__ Uo,
    float* __restrict__ out, unsigned* __restrict__ h_buf)
{
  extern __shared__ _Float16 lds[];
  _Float16* U_lds = lds;                       // 64 rows x SH   (row = g*16+jj)
  _Float16* h_lds = lds + 64*SH;               // 8 rows x SH
  float*  act_buf = (float*)(lds + 72*SH);     // 8*16*2 f32 activated i,o exchange

  int tid = threadIdx.x;
  int grp = blockIdx.x & 7;
  int member = blockIdx.x >> 3;
  int j0 = member * 16;

  { // one-time: stage U columns transposed into LDS, f32 -> f16
    int jj = tid & 15;
    int kk = tid >> 4;
    #pragma unroll
    for (int g = 0; g < 4; ++g) {
      const float* U = (g==0) ? Uc : (g==1) ? Ui : (g==2) ? Uf : Uo;
      _Float16* dst = &U_lds[(g*16 + jj)*SH];
      for (int k = kk; k < H_; k += 16)
        dst[k] = (_Float16)U[(size_t)k * H_ + j0 + jj];
    }
  }
  __syncthreads();

  int b   = tid & 7;
  int jj  = (tid >> 3) & 15;
  int gh  = tid >> 7;             // wave-uniform: 0 -> (a,f); 1 -> (i,o)
  int bglob = grp*8 + b;
  int j = j0 + jj;

  const half8* Ur0 = (const half8*)&U_lds[((gh    )*16 + jj)*SH];
  const half8* Ur1 = (const half8*)&U_lds[((gh + 2)*16 + jj)*SH];
  const half8* Hr  = (const half8*)&h_lds[b*SH];

  // staging geometry: thread covers 16 consecutive cols of one batch row
  int srow = tid >> 5;            // 0..7
  int sc0  = (tid & 31) * 16;

  float c_reg = 0.0f;

  for (int t = 0; t < T_; ++t) {
    // ---- stage h^t: sweep-parallel tagged poll, then LDS write ----
    {
      const unsigned long long* src8 = (const unsigned long long*)
          &h_buf[(size_t)(t & 1)*(B_*H_) + (size_t)(grp*8 + srow)*H_ + sc0];
      unsigned long long want2 = (unsigned long long)((unsigned)t & 0xFFFFu);
      want2 |= want2 << 32;
      unsigned long long w8[8];
      for (;;) {
        #pragma unroll
        for (int q = 0; q < 8; ++q)
          w8[q] = __hip_atomic_load(&src8[q], __ATOMIC_RELAXED,
                                    __HIP_MEMORY_SCOPE_AGENT);
        unsigned long long diff = 0;
        #pragma unroll
        for (int q = 0; q < 8; ++q)
          diff |= (w8[q] ^ want2) & 0x0000FFFF0000FFFFull;
        if (diff == 0) break;
      }
      half8 hv0, hv1;
      #pragma unroll
      for (int q = 0; q < 4; ++q) {
        hv0[2*q]   = __builtin_bit_cast(_Float16, (unsigned short)(w8[q]   >> 16));
        hv0[2*q+1] = __builtin_bit_cast(_Float16, (unsigned short)(w8[q]   >> 48));
        hv1[2*q]   = __builtin_bit_cast(_Float16, (unsigned short)(w8[4+q] >> 16));
        hv1[2*q+1] = __builtin_bit_cast(_Float16, (unsigned short)(w8[4+q] >> 48));
      }
      *(half8*)&h_lds[srow*SH + sc0]     = hv0;
      *(half8*)&h_lds[srow*SH + sc0 + 8] = hv1;
    }
    __syncthreads();   // staged h visible

    size_t xb = ((size_t)t * B_ + bglob) * NG;
    float xg0 = (float)XG[xb + (size_t)gh*H_ + j];
    float xg1 = (float)XG[xb + (size_t)(gh + 2)*H_ + j];

    float acc0 = 0.f, acc1 = 0.f;
    #pragma unroll 4
    for (int k8 = 0; k8 < H_/8; ++k8) {
      half8 hv = Hr[k8];
      half8 u0 = Ur0[k8];
      half8 u1 = Ur1[k8];
      #pragma unroll
      for (int i = 0; i < 4; ++i) {
        acc0 = fdot2_acc(h2(hv,i), h2(u0,i), acc0);
        acc1 = fdot2_acc(h2(hv,i), h2(u1,i), acc1);
      }
    }
    float pre0 = acc0 + xg0;     // gh0: a-gate   gh1: i-gate
    float pre1 = acc1 + xg1;     // gh0: f-gate   gh1: o-gate

    // both halves do their transcendentals BEFORE the exchange barrier
    float act0 = (gh == 0) ? fast_tanh(pre0) : fast_sigmoid(pre0);
    float act1 = fast_sigmoid(pre1);

    if (gh == 1) {
      act_buf[(b*16 + jj)*2    ] = act0;   // sigmoid(i)
      act_buf[(b*16 + jj)*2 + 1] = act1;   // sigmoid(o)
    }
    __syncthreads();   // act_buf visible; all h_lds reads done

    if (gh == 0) {
      float iv = act_buf[(b*16 + jj)*2];
      float ov = act_buf[(b*16 + jj)*2 + 1];
      float cn = fmaf(act1, c_reg, iv * act0);   // f*c + i*a
      c_reg = cn;
      float hval = ov * fast_tanh(cn);
      if (t + 1 < T_) {   // publish FIRST (critical path), out store after
        unsigned wv = ((unsigned)__builtin_bit_cast(unsigned short, (_Float16)hval) << 16)
                    | ((unsigned)(t + 1) & 0xFFFFu);
        __hip_atomic_store(&h_buf[(size_t)((t + 1) & 1)*(B_*H_) + (size_t)bglob*H_ + j],
                           wv, __ATOMIC_RELAXED, __HIP_MEMORY_SCOPE_AGENT);
      }
      out[((size_t)bglob * T_ + t) * H_ + j] = hval;
    }
  }
}

// ---------------------------------------------------------------------------
extern "C" void kernel_launch(void* const* d_in, const int* in_sizes, int n_in,
                              void* d_out, int out_size, void* d_ws, size_t ws_size,
                              hipStream_t stream)
{
  const float* x  = (const float*)d_in[0];
  const float* Wc = (const float*)d_in[1];
  const float* Wi = (const float*)d_in[2];
  const float* Wf = (const float*)d_in[3];
  const float* Wo = (const float*)d_in[4];
  const float* Uc = (const float*)d_in[5];
  const float* Ui = (const float*)d_in[6];
  const float* Uf = (const float*)d_in[7];
  const float* Uo = (const float*)d_in[8];
  const float* bc = (const float*)d_in[9];
  const float* bi = (const float*)d_in[10];
  const float* bf2= (const float*)d_in[11];
  const float* bo = (const float*)d_in[12];
  float* out = (float*)d_out;

  const size_t XG_BYTES = (size_t)T_ * B_ * NG * sizeof(_Float16);  // 128 MiB
  const size_t HB_BYTES = (size_t)2 * B_ * H_ * sizeof(unsigned);   // 256 KiB

  if (ws_size < XG_BYTES + HB_BYTES) return;

  _Float16* XG   = (_Float16*)d_ws;
  unsigned* hbuf = (unsigned*)((char*)d_ws + XG_BYTES);

  // tag 0 / h=0 initial state; also kills cross-replay tag aliasing
  (void)hipMemsetAsync(hbuf, 0, HB_BYTES, stream);

  proj_kernel<<<dim3((T_*B_/64) * (NG/64)), dim3(256), 0, stream>>>(
      x, Wc, Wi, Wf, Wo, bc, bi, bf2, bo, XG);

  const int lds_bytes = 72*SH*2 + 8*16*2*4;   // 75,904 B
  (void)hipFuncSetAttribute(reinterpret_cast<const void*>(scan_kernel),
                      hipFuncAttributeMaxDynamicSharedMemorySize, lds_bytes);
  scan_kernel<<<dim3(256), dim3(256), lds_bytes, stream>>>(
      XG, Uc, Ui, Uf, Uo, out, hbuf);
}